// Round 9
// baseline (538.614 us; speedup 1.0000x reference)
//
#include <hip/hip_runtime.h>

// Problem constants (match reference)
constexpr int   N_NODES = 80000;
constexpr int   N_EDGE  = 2560000;
constexpr int   IN_DIM  = 128;
constexpr int   H1      = 32;
constexpr int   H2      = 64;
constexpr int   NPB     = 10000;   // nodes per batch
constexpr int   NB      = 8;       // batches
constexpr int   G2_BLOCKS = N_NODES / 4;        // 20000 (4 nodes per block)
constexpr int   BLK_PER_BATCH = G2_BLOCKS / NB; // 2500
constexpr int   SCAN_B   = 256;
constexpr int   SCAN_NBLK = (N_NODES + SCAN_B - 1) / SCAN_B;  // 313

// ---------------- init: ecnt = 0 ----------------
__global__ void k_init(unsigned* __restrict__ ecnt) {
    int i = blockIdx.x * blockDim.x + threadIdx.x;
    if (i < N_NODES) ecnt[i] = 0u;
}

// ---------------- degree count (edges only): ecnt[dst]++ ----------------
__global__ void k_deg(const int* __restrict__ ei, unsigned* __restrict__ ecnt) {
    int e = blockIdx.x * blockDim.x + threadIdx.x;
    if (e >= N_EDGE) return;
    atomicAdd(&ecnt[ei[N_EDGE + e]], 1u);
}

// ------- scan phase 1: block-local scan + block totals; fused dinv --------
__global__ __launch_bounds__(SCAN_B) void k_scan1(
        const unsigned* __restrict__ ecnt, unsigned* __restrict__ excl,
        unsigned* __restrict__ blocksum, float* __restrict__ dinv) {
    __shared__ unsigned tmp[SCAN_B];
    int t = threadIdx.x;
    int i = blockIdx.x * SCAN_B + t;
    unsigned v = (i < N_NODES) ? ecnt[i] : 0u;
    tmp[t] = v;
    for (int ofs = 1; ofs < SCAN_B; ofs <<= 1) {
        __syncthreads();
        unsigned u = (t >= ofs) ? tmp[t - ofs] : 0u;
        __syncthreads();
        tmp[t] += u;
    }
    __syncthreads();
    if (i < N_NODES) {
        excl[i] = tmp[t] - v;                  // exclusive within block
        dinv[i] = rsqrtf((float)(v + 1u));     // fused: +1 self loop
    }
    if (t == SCAN_B - 1) blocksum[blockIdx.x] = tmp[t];
}

// ------- scan phase 2: scan the 313 block totals in-place (1 block) -------
__global__ __launch_bounds__(512) void k_scan2(unsigned* __restrict__ blocksum) {
    __shared__ unsigned tmp[512];
    int t = threadIdx.x;
    unsigned v = (t < SCAN_NBLK) ? blocksum[t] : 0u;
    tmp[t] = v;
    for (int ofs = 1; ofs < 512; ofs <<= 1) {
        __syncthreads();
        unsigned u = (t >= ofs) ? tmp[t - ofs] : 0u;
        __syncthreads();
        tmp[t] += u;
    }
    __syncthreads();
    if (t < SCAN_NBLK) blocksum[t] = tmp[t] - v;   // exclusive block base
}

// ------- scan phase 3: row_ptr = excl + base; bump = row_ptr --------------
__global__ __launch_bounds__(SCAN_B) void k_scan3(
        const unsigned* __restrict__ excl, const unsigned* __restrict__ blocksum,
        unsigned* __restrict__ row_ptr, unsigned* __restrict__ bump) {
    int i = blockIdx.x * SCAN_B + threadIdx.x;
    if (i < N_NODES) {
        unsigned r = excl[i] + blocksum[blockIdx.x];
        row_ptr[i] = r;
        bump[i]    = r;
    }
    if (i == 0) row_ptr[N_NODES] = (unsigned)N_EDGE;
}

// ---------------- bucket fill: csr[pos] = src (4 B payload) ----------------
// norm is folded into the pre-scaled node arrays (xW1s/h2s) and dinv[d].
__global__ void k_fill(const int* __restrict__ ei,
                       unsigned* __restrict__ bump, int* __restrict__ csr) {
    int e = blockIdx.x * blockDim.x + threadIdx.x;
    if (e >= N_EDGE) return;
    int s = ei[e];
    int d = ei[N_EDGE + e];
    unsigned pos = atomicAdd(&bump[d], 1u);
    csr[pos] = s;
}

// ---------------- GEMM1: xW1s = (x @ W1) * dinv[row]  (pre-scaled) --------
__global__ __launch_bounds__(256) void k_gemm1(
        const float* __restrict__ x, const float* __restrict__ W1,
        const float* __restrict__ dinv, float* __restrict__ xW1s) {
    __shared__ float W1s[IN_DIM * H1];   // 16 KB
    int tid = threadIdx.x;
    for (int i = tid; i < IN_DIM * H1; i += 256) W1s[i] = W1[i];
    __syncthreads();
    int r = tid >> 5, c = tid & 31;
    int row = blockIdx.x * 8 + r;
    if (row >= N_NODES) return;
    const float4* x4 = reinterpret_cast<const float4*>(x + (long long)row * IN_DIM);
    float acc = 0.f;
#pragma unroll
    for (int j = 0; j < IN_DIM / 4; ++j) {
        float4 xv = x4[j];
        acc += xv.x * W1s[(4 * j + 0) * H1 + c];
        acc += xv.y * W1s[(4 * j + 1) * H1 + c];
        acc += xv.z * W1s[(4 * j + 2) * H1 + c];
        acc += xv.w * W1s[(4 * j + 3) * H1 + c];
    }
    xW1s[row * H1 + c] = acc * dinv[row];
}

// ------- gather layer 1: agg1[d] = dinv[d] * (sum_e xW1s[src_e] + xW1s[d]) --
// Octet-wave mapping: o = lane>>3 (edge slot 0..7), t = lane&7 (feature quad).
__global__ __launch_bounds__(256) void k_gather1(
        const unsigned* __restrict__ row_ptr, const int* __restrict__ csr,
        const float* __restrict__ xW1s, const float* __restrict__ dinv,
        float* __restrict__ agg1) {
    int wave = threadIdx.x >> 6;
    int lane = threadIdx.x & 63;
    int o = lane >> 3, t = lane & 7;
    int d = blockIdx.x * 4 + wave;
    if (d >= N_NODES) return;
    unsigned beg = row_ptr[d], end = row_ptr[d + 1];
    float4 acc = make_float4(0.f, 0.f, 0.f, 0.f);
    for (unsigned j = beg; j < end; j += 16) {
        unsigned j0 = j + (unsigned)o;
        unsigned j1 = j0 + 8u;
        int   s0 = (j0 < end) ? csr[j0] : 0;
        float m0 = (j0 < end) ? 1.f : 0.f;
        int   s1 = (j1 < end) ? csr[j1] : 0;
        float m1 = (j1 < end) ? 1.f : 0.f;
        float4 r0 = *reinterpret_cast<const float4*>(xW1s + (size_t)s0 * H1 + 4 * t);
        float4 r1 = *reinterpret_cast<const float4*>(xW1s + (size_t)s1 * H1 + 4 * t);
        acc.x += r0.x * m0 + r1.x * m1;
        acc.y += r0.y * m0 + r1.y * m1;
        acc.z += r0.z * m0 + r1.z * m1;
        acc.w += r0.w * m0 + r1.w * m1;
    }
#pragma unroll
    for (int m = 8; m <= 32; m <<= 1) {
        acc.x += __shfl_xor(acc.x, m, 64);
        acc.y += __shfl_xor(acc.y, m, 64);
        acc.z += __shfl_xor(acc.z, m, 64);
        acc.w += __shfl_xor(acc.w, m, 64);
    }
    if (lane < 8) {   // o == 0 octet writes the 32-feature row as 8x float4
        float dv = dinv[d];
        float4 self = *reinterpret_cast<const float4*>(xW1s + (size_t)d * H1 + 4 * t);
        float4 outv;
        outv.x = (acc.x + self.x) * dv;
        outv.y = (acc.y + self.y) * dv;
        outv.z = (acc.z + self.z) * dv;
        outv.w = (acc.w + self.w) * dv;
        *reinterpret_cast<float4*>(agg1 + (size_t)d * H1 + 4 * t) = outv;
    }
}

// ------- GEMM2: h2s = (relu(agg1+b1) @ W2) * dinv[row]  (pre-scaled) ------
__global__ __launch_bounds__(256) void k_gemm2(
        const float* __restrict__ agg1, const float* __restrict__ b1,
        const float* __restrict__ W2, const float* __restrict__ dinv,
        float* __restrict__ h2s) {
    __shared__ float W2s[H1 * H2];   // 8 KB
    __shared__ float b1s[H1];
    int tid = threadIdx.x;
    for (int i = tid; i < H1 * H2; i += 256) W2s[i] = W2[i];
    if (tid < H1) b1s[tid] = b1[tid];
    __syncthreads();
    int r = tid >> 6, c = tid & 63;
    int row = blockIdx.x * 4 + r;
    if (row >= N_NODES) return;
    float acc = 0.f;
#pragma unroll
    for (int k = 0; k < H1; ++k) {
        float hk = fmaxf(agg1[row * H1 + k] + b1s[k], 0.f);
        acc += hk * W2s[k * H2 + c];
    }
    h2s[row * H2 + c] = acc * dinv[row];
}

// ------- gather layer 2 FUSED with readout -------
// agg2 = dinv[d] * (sum_e h2s[src_e] + h2s[d]);
// partial2[block] = sum over 4 nodes of sum_f relu(agg2+b2)*Wout — plain store.
__global__ __launch_bounds__(256) void k_gather2_final(
        const unsigned* __restrict__ row_ptr, const int* __restrict__ csr,
        const float* __restrict__ h2s, const float* __restrict__ dinv,
        const float* __restrict__ b2, const float* __restrict__ Wout,
        double* __restrict__ partial2) {
    int wave = threadIdx.x >> 6;
    int lane = threadIdx.x & 63;
    int q = lane >> 4, t = lane & 15;
    int d = blockIdx.x * 4 + wave;
    unsigned beg = row_ptr[d], end = row_ptr[d + 1];
    float4 acc = make_float4(0.f, 0.f, 0.f, 0.f);
    for (unsigned j = beg; j < end; j += 8) {
        unsigned j0 = j + (unsigned)q;
        unsigned j1 = j0 + 4u;
        int   s0 = (j0 < end) ? csr[j0] : 0;
        float m0 = (j0 < end) ? 1.f : 0.f;
        int   s1 = (j1 < end) ? csr[j1] : 0;
        float m1 = (j1 < end) ? 1.f : 0.f;
        float4 r0 = *reinterpret_cast<const float4*>(h2s + (size_t)s0 * H2 + 4 * t);
        float4 r1 = *reinterpret_cast<const float4*>(h2s + (size_t)s1 * H2 + 4 * t);
        acc.x += r0.x * m0 + r1.x * m1;
        acc.y += r0.y * m0 + r1.y * m1;
        acc.z += r0.z * m0 + r1.z * m1;
        acc.w += r0.w * m0 + r1.w * m1;
    }
#pragma unroll
    for (int m = 16; m <= 32; m <<= 1) {
        acc.x += __shfl_xor(acc.x, m, 64);
        acc.y += __shfl_xor(acc.y, m, 64);
        acc.z += __shfl_xor(acc.z, m, 64);
        acc.w += __shfl_xor(acc.w, m, 64);
    }
    float dv = dinv[d];
    float4 self = *reinterpret_cast<const float4*>(h2s + (size_t)d * H2 + 4 * t);
    float4 bb   = *reinterpret_cast<const float4*>(b2 + 4 * t);
    float4 ww   = *reinterpret_cast<const float4*>(Wout + (size_t)(d % NPB) * H2 + 4 * t);
    float v0 = fmaxf((acc.x + self.x) * dv + bb.x, 0.f) * ww.x;
    float v1 = fmaxf((acc.y + self.y) * dv + bb.y, 0.f) * ww.y;
    float v2 = fmaxf((acc.z + self.z) * dv + bb.z, 0.f) * ww.z;
    float v3 = fmaxf((acc.w + self.w) * dv + bb.w, 0.f) * ww.w;
    double dval = (double)v0 + (double)v1 + (double)v2 + (double)v3;
    dval += __shfl_down(dval, 8, 64);
    dval += __shfl_down(dval, 4, 64);
    dval += __shfl_down(dval, 2, 64);
    dval += __shfl_down(dval, 1, 64);
    __shared__ double sdbl[4];
    if (lane == 0) sdbl[wave] = dval;
    __syncthreads();
    if (threadIdx.x == 0)
        partial2[blockIdx.x] = (sdbl[0] + sdbl[1]) + (sdbl[2] + sdbl[3]);
}

// ------- final reduce: out[b] = sum of partial2[b*2500 .. ) + bout -------
__global__ __launch_bounds__(256) void k_reduce(
        const double* __restrict__ partial2, const float* __restrict__ bout,
        float* __restrict__ out) {
    int b = blockIdx.x;
    int tid = threadIdx.x;
    double acc = 0.0;
    for (int i = tid; i < BLK_PER_BATCH; i += 256)
        acc += partial2[b * BLK_PER_BATCH + i];
    for (int off = 32; off; off >>= 1) acc += __shfl_down(acc, off, 64);
    __shared__ double sred[4];
    if ((tid & 63) == 0) sred[tid >> 6] = acc;
    __syncthreads();
    if (tid == 0)
        out[b] = (float)(((sred[0] + sred[1]) + (sred[2] + sred[3])) + (double)bout[0]);
}

extern "C" void kernel_launch(void* const* d_in, const int* in_sizes, int n_in,
                              void* d_out, int out_size, void* d_ws, size_t ws_size,
                              hipStream_t stream) {
    const float* x    = (const float*)d_in[0];
    const int*   ei   = (const int*)d_in[1];    // int32 (JAX x64 disabled)
    const float* W1   = (const float*)d_in[2];
    const float* b1   = (const float*)d_in[3];
    const float* W2   = (const float*)d_in[4];
    const float* b2   = (const float*)d_in[5];
    const float* Wout = (const float*)d_in[6];
    const float* bout = (const float*)d_in[7];
    float* out = (float*)d_out;

    // workspace layout — no aliasing, total ~53.3 MB
    char* ws = (char*)d_ws;
    size_t off = 0;
    int*      csr     = (int*)(ws + off);      off += (size_t)N_EDGE * 4;        // 10.24 MB
    float*    xW1s    = (float*)(ws + off);    off += (size_t)N_NODES * H1 * 4;  // 10.24 MB
    float*    agg1    = (float*)(ws + off);    off += (size_t)N_NODES * H1 * 4;  // 10.24 MB
    float*    h2s     = (float*)(ws + off);    off += (size_t)N_NODES * H2 * 4;  // 20.48 MB
    unsigned* ecnt    = (unsigned*)(ws + off); off += (size_t)N_NODES * 4;       // 0.32 MB
    unsigned* row_ptr = (unsigned*)(ws + off); off += (size_t)(N_NODES + 16) * 4;// 0.32 MB
    unsigned* bump    = (unsigned*)(ws + off); off += (size_t)N_NODES * 4;       // 0.32 MB
    float*    dinv    = (float*)(ws + off);    off += (size_t)N_NODES * 4;       // 0.32 MB
    unsigned* excl    = (unsigned*)(ws + off); off += (size_t)N_NODES * 4;       // 0.32 MB
    unsigned* blocksum= (unsigned*)(ws + off); off += 512 * 4;
    double*   partial2= (double*)(ws + off);   off += (size_t)G2_BLOCKS * 8;     // 0.16 MB
    (void)ws_size; (void)in_sizes; (void)n_in; (void)out_size;

    const int B = 256;
    k_init<<<(N_NODES + B - 1) / B, B, 0, stream>>>(ecnt);
    k_deg<<<(N_EDGE + B - 1) / B, B, 0, stream>>>(ei, ecnt);
    k_scan1<<<SCAN_NBLK, SCAN_B, 0, stream>>>(ecnt, excl, blocksum, dinv);
    k_scan2<<<1, 512, 0, stream>>>(blocksum);
    k_scan3<<<SCAN_NBLK, SCAN_B, 0, stream>>>(excl, blocksum, row_ptr, bump);
    k_fill<<<(N_EDGE + B - 1) / B, B, 0, stream>>>(ei, bump, csr);

    k_gemm1<<<N_NODES / 8, B, 0, stream>>>(x, W1, dinv, xW1s);
    k_gather1<<<N_NODES / 4, B, 0, stream>>>(row_ptr, csr, xW1s, dinv, agg1);
    k_gemm2<<<N_NODES / 4, B, 0, stream>>>(agg1, b1, W2, dinv, h2s);
    k_gather2_final<<<G2_BLOCKS, B, 0, stream>>>(row_ptr, csr, h2s, dinv, b2, Wout, partial2);

    k_reduce<<<NB, B, 0, stream>>>(partial2, bout, out);
}

// Round 10
// 389.880 us; speedup vs baseline: 1.3815x; 1.3815x over previous
//
#include <hip/hip_runtime.h>

// Problem constants (match reference)
constexpr int   N_NODES = 80000;
constexpr int   N_EDGE  = 2560000;
constexpr int   IN_DIM  = 128;
constexpr int   H1      = 32;
constexpr int   H2      = 64;
constexpr int   NPB     = 10000;   // nodes per batch
constexpr int   NB      = 8;       // batches
constexpr int   G2_BLOCKS = N_NODES / 4;        // 20000 (4 nodes per block)
constexpr int   BLK_PER_BATCH = G2_BLOCKS / NB; // 2500
constexpr int   SCAN_B   = 256;
constexpr int   SCAN_NBLK = (N_NODES + SCAN_B - 1) / SCAN_B;  // 313

// binned-fill parameters
constexpr int   BKT_SHIFT = 7;                       // 128 nodes per bucket
constexpr int   NBKT      = N_NODES >> BKT_SHIFT;    // 625 (exact: 625*128=80000)
constexpr int   BBSTRIDE  = 16;                      // pad bucket counters to 64 B
constexpr int   BF_EPB    = 8192;                    // edges per binfill block
constexpr int   BF_BLOCKS = (N_EDGE + BF_EPB - 1) / BF_EPB;  // 313

// ---------------- init: ecnt = 0 ----------------
__global__ void k_init(unsigned* __restrict__ ecnt) {
    int i = blockIdx.x * blockDim.x + threadIdx.x;
    if (i < N_NODES) ecnt[i] = 0u;
}

// ---------------- degree count (edges only): ecnt[dst]++ ----------------
__global__ void k_deg(const int* __restrict__ ei, unsigned* __restrict__ ecnt) {
    int e = blockIdx.x * blockDim.x + threadIdx.x;
    if (e >= N_EDGE) return;
    atomicAdd(&ecnt[ei[N_EDGE + e]], 1u);
}

// ------- scan phase 1: block-local scan + block totals; fused dinv --------
__global__ __launch_bounds__(SCAN_B) void k_scan1(
        const unsigned* __restrict__ ecnt, unsigned* __restrict__ excl,
        unsigned* __restrict__ blocksum, float* __restrict__ dinv) {
    __shared__ unsigned tmp[SCAN_B];
    int t = threadIdx.x;
    int i = blockIdx.x * SCAN_B + t;
    unsigned v = (i < N_NODES) ? ecnt[i] : 0u;
    tmp[t] = v;
    for (int ofs = 1; ofs < SCAN_B; ofs <<= 1) {
        __syncthreads();
        unsigned u = (t >= ofs) ? tmp[t - ofs] : 0u;
        __syncthreads();
        tmp[t] += u;
    }
    __syncthreads();
    if (i < N_NODES) {
        excl[i] = tmp[t] - v;                  // exclusive within block
        dinv[i] = rsqrtf((float)(v + 1u));     // fused: +1 self loop
    }
    if (t == SCAN_B - 1) blocksum[blockIdx.x] = tmp[t];
}

// ------- scan phase 2: scan the 313 block totals in-place (1 block) -------
__global__ __launch_bounds__(512) void k_scan2(unsigned* __restrict__ blocksum) {
    __shared__ unsigned tmp[512];
    int t = threadIdx.x;
    unsigned v = (t < SCAN_NBLK) ? blocksum[t] : 0u;
    tmp[t] = v;
    for (int ofs = 1; ofs < 512; ofs <<= 1) {
        __syncthreads();
        unsigned u = (t >= ofs) ? tmp[t - ofs] : 0u;
        __syncthreads();
        tmp[t] += u;
    }
    __syncthreads();
    if (t < SCAN_NBLK) blocksum[t] = tmp[t] - v;   // exclusive block base
}

// ------- scan phase 3: row_ptr = excl + base; seed padded bucket bumps ----
__global__ __launch_bounds__(SCAN_B) void k_scan3(
        const unsigned* __restrict__ excl, const unsigned* __restrict__ blocksum,
        unsigned* __restrict__ row_ptr, unsigned* __restrict__ bbump) {
    int i = blockIdx.x * SCAN_B + threadIdx.x;
    if (i < N_NODES) {
        unsigned r = excl[i] + blocksum[blockIdx.x];
        row_ptr[i] = r;
        if ((i & ((1 << BKT_SHIFT) - 1)) == 0)
            bbump[(i >> BKT_SHIFT) * BBSTRIDE] = r;   // bucket base
    }
    if (i == 0) row_ptr[N_NODES] = (unsigned)N_EDGE;
}

// ------- binned fill pass B: stage[pos] = (src<<7)|d_local, dense writes ---
__global__ __launch_bounds__(256) void k_binfill(
        const int* __restrict__ ei, unsigned* __restrict__ bbump,
        unsigned* __restrict__ stage) {
    __shared__ unsigned hist[NBKT];
    __shared__ unsigned base[NBKT];
    int t = threadIdx.x;
    int e0 = blockIdx.x * BF_EPB;
    int e1 = min(e0 + BF_EPB, N_EDGE);
    for (int i = t; i < NBKT; i += 256) hist[i] = 0u;
    __syncthreads();
    // phase 1: local histogram over dst buckets
    for (int e = e0 + t; e < e1; e += 256) {
        int d = ei[N_EDGE + e];
        atomicAdd(&hist[d >> BKT_SHIFT], 1u);
    }
    __syncthreads();
    // phase 2: reserve global ranges (one atomic per non-empty bucket)
    for (int i = t; i < NBKT; i += 256) {
        unsigned h = hist[i];
        base[i] = h ? atomicAdd(&bbump[i * BBSTRIDE], h) : 0u;
        hist[i] = 0u;
    }
    __syncthreads();
    // phase 3: place edges into reserved ranges (dense per bucket)
    for (int e = e0 + t; e < e1; e += 256) {
        int s = ei[e];
        int d = ei[N_EDGE + e];
        int bkt = d >> BKT_SHIFT;
        unsigned lp = atomicAdd(&hist[bkt], 1u);
        stage[base[bkt] + lp] =
            ((unsigned)s << BKT_SHIFT) | (unsigned)(d & ((1 << BKT_SHIFT) - 1));
    }
}

// ------- binned fill pass C: per-bucket exact placement (LDS bumps) -------
__global__ __launch_bounds__(256) void k_place(
        const unsigned* __restrict__ row_ptr, const unsigned* __restrict__ stage,
        int* __restrict__ csr) {
    __shared__ unsigned nb[(1 << BKT_SHIFT) + 1];   // 129 node bases
    int b = blockIdx.x;
    int t = threadIdx.x;
    int n0 = b << BKT_SHIFT;
    for (int i = t; i < (1 << BKT_SHIFT) + 1; i += 256) nb[i] = row_ptr[n0 + i];
    __syncthreads();
    unsigned beg = nb[0], end = nb[1 << BKT_SHIFT];
    __syncthreads();   // all threads must read beg/end before any bump
    for (unsigned j = beg + (unsigned)t; j < end; j += 256) {
        unsigned v = stage[j];
        unsigned dl = v & ((1u << BKT_SHIFT) - 1u);
        unsigned pos = atomicAdd(&nb[dl], 1u);
        csr[pos] = (int)(v >> BKT_SHIFT);
    }
}

// ---------------- GEMM1: xW1s = (x @ W1) * dinv[row]  (pre-scaled) --------
__global__ __launch_bounds__(256) void k_gemm1(
        const float* __restrict__ x, const float* __restrict__ W1,
        const float* __restrict__ dinv, float* __restrict__ xW1s) {
    __shared__ float W1s[IN_DIM * H1];   // 16 KB
    int tid = threadIdx.x;
    for (int i = tid; i < IN_DIM * H1; i += 256) W1s[i] = W1[i];
    __syncthreads();
    int r = tid >> 5, c = tid & 31;
    int row = blockIdx.x * 8 + r;
    if (row >= N_NODES) return;
    const float4* x4 = reinterpret_cast<const float4*>(x + (long long)row * IN_DIM);
    float acc = 0.f;
#pragma unroll
    for (int j = 0; j < IN_DIM / 4; ++j) {
        float4 xv = x4[j];
        acc += xv.x * W1s[(4 * j + 0) * H1 + c];
        acc += xv.y * W1s[(4 * j + 1) * H1 + c];
        acc += xv.z * W1s[(4 * j + 2) * H1 + c];
        acc += xv.w * W1s[(4 * j + 3) * H1 + c];
    }
    xW1s[row * H1 + c] = acc * dinv[row];
}

// ------- gather layer 1: agg1[d] = dinv[d] * (sum_e xW1s[src_e] + xW1s[d]) --
__global__ __launch_bounds__(256) void k_gather1(
        const unsigned* __restrict__ row_ptr, const int* __restrict__ csr,
        const float* __restrict__ xW1s, const float* __restrict__ dinv,
        float* __restrict__ agg1) {
    int wave = threadIdx.x >> 6;
    int lane = threadIdx.x & 63;
    int o = lane >> 3, t = lane & 7;
    int d = blockIdx.x * 4 + wave;
    if (d >= N_NODES) return;
    unsigned beg = row_ptr[d], end = row_ptr[d + 1];
    float4 acc = make_float4(0.f, 0.f, 0.f, 0.f);
    for (unsigned j = beg; j < end; j += 16) {
        unsigned j0 = j + (unsigned)o;
        unsigned j1 = j0 + 8u;
        int   s0 = (j0 < end) ? csr[j0] : 0;
        float m0 = (j0 < end) ? 1.f : 0.f;
        int   s1 = (j1 < end) ? csr[j1] : 0;
        float m1 = (j1 < end) ? 1.f : 0.f;
        float4 r0 = *reinterpret_cast<const float4*>(xW1s + (size_t)s0 * H1 + 4 * t);
        float4 r1 = *reinterpret_cast<const float4*>(xW1s + (size_t)s1 * H1 + 4 * t);
        acc.x += r0.x * m0 + r1.x * m1;
        acc.y += r0.y * m0 + r1.y * m1;
        acc.z += r0.z * m0 + r1.z * m1;
        acc.w += r0.w * m0 + r1.w * m1;
    }
#pragma unroll
    for (int m = 8; m <= 32; m <<= 1) {
        acc.x += __shfl_xor(acc.x, m, 64);
        acc.y += __shfl_xor(acc.y, m, 64);
        acc.z += __shfl_xor(acc.z, m, 64);
        acc.w += __shfl_xor(acc.w, m, 64);
    }
    if (lane < 8) {   // o == 0 octet writes the 32-feature row as 8x float4
        float dv = dinv[d];
        float4 self = *reinterpret_cast<const float4*>(xW1s + (size_t)d * H1 + 4 * t);
        float4 outv;
        outv.x = (acc.x + self.x) * dv;
        outv.y = (acc.y + self.y) * dv;
        outv.z = (acc.z + self.z) * dv;
        outv.w = (acc.w + self.w) * dv;
        *reinterpret_cast<float4*>(agg1 + (size_t)d * H1 + 4 * t) = outv;
    }
}

// ------- GEMM2: h2s = (relu(agg1+b1) @ W2) * dinv[row]  (pre-scaled) ------
__global__ __launch_bounds__(256) void k_gemm2(
        const float* __restrict__ agg1, const float* __restrict__ b1,
        const float* __restrict__ W2, const float* __restrict__ dinv,
        float* __restrict__ h2s) {
    __shared__ float W2s[H1 * H2];   // 8 KB
    __shared__ float b1s[H1];
    int tid = threadIdx.x;
    for (int i = tid; i < H1 * H2; i += 256) W2s[i] = W2[i];
    if (tid < H1) b1s[tid] = b1[tid];
    __syncthreads();
    int r = tid >> 6, c = tid & 63;
    int row = blockIdx.x * 4 + r;
    if (row >= N_NODES) return;
    float acc = 0.f;
#pragma unroll
    for (int k = 0; k < H1; ++k) {
        float hk = fmaxf(agg1[row * H1 + k] + b1s[k], 0.f);
        acc += hk * W2s[k * H2 + c];
    }
    h2s[row * H2 + c] = acc * dinv[row];
}

// ------- gather layer 2 FUSED with readout -------
__global__ __launch_bounds__(256) void k_gather2_final(
        const unsigned* __restrict__ row_ptr, const int* __restrict__ csr,
        const float* __restrict__ h2s, const float* __restrict__ dinv,
        const float* __restrict__ b2, const float* __restrict__ Wout,
        double* __restrict__ partial2) {
    int wave = threadIdx.x >> 6;
    int lane = threadIdx.x & 63;
    int q = lane >> 4, t = lane & 15;
    int d = blockIdx.x * 4 + wave;
    unsigned beg = row_ptr[d], end = row_ptr[d + 1];
    float4 acc = make_float4(0.f, 0.f, 0.f, 0.f);
    for (unsigned j = beg; j < end; j += 8) {
        unsigned j0 = j + (unsigned)q;
        unsigned j1 = j0 + 4u;
        int   s0 = (j0 < end) ? csr[j0] : 0;
        float m0 = (j0 < end) ? 1.f : 0.f;
        int   s1 = (j1 < end) ? csr[j1] : 0;
        float m1 = (j1 < end) ? 1.f : 0.f;
        float4 r0 = *reinterpret_cast<const float4*>(h2s + (size_t)s0 * H2 + 4 * t);
        float4 r1 = *reinterpret_cast<const float4*>(h2s + (size_t)s1 * H2 + 4 * t);
        acc.x += r0.x * m0 + r1.x * m1;
        acc.y += r0.y * m0 + r1.y * m1;
        acc.z += r0.z * m0 + r1.z * m1;
        acc.w += r0.w * m0 + r1.w * m1;
    }
#pragma unroll
    for (int m = 16; m <= 32; m <<= 1) {
        acc.x += __shfl_xor(acc.x, m, 64);
        acc.y += __shfl_xor(acc.y, m, 64);
        acc.z += __shfl_xor(acc.z, m, 64);
        acc.w += __shfl_xor(acc.w, m, 64);
    }
    float dv = dinv[d];
    float4 self = *reinterpret_cast<const float4*>(h2s + (size_t)d * H2 + 4 * t);
    float4 bb   = *reinterpret_cast<const float4*>(b2 + 4 * t);
    float4 ww   = *reinterpret_cast<const float4*>(Wout + (size_t)(d % NPB) * H2 + 4 * t);
    float v0 = fmaxf((acc.x + self.x) * dv + bb.x, 0.f) * ww.x;
    float v1 = fmaxf((acc.y + self.y) * dv + bb.y, 0.f) * ww.y;
    float v2 = fmaxf((acc.z + self.z) * dv + bb.z, 0.f) * ww.z;
    float v3 = fmaxf((acc.w + self.w) * dv + bb.w, 0.f) * ww.w;
    double dval = (double)v0 + (double)v1 + (double)v2 + (double)v3;
    dval += __shfl_down(dval, 8, 64);
    dval += __shfl_down(dval, 4, 64);
    dval += __shfl_down(dval, 2, 64);
    dval += __shfl_down(dval, 1, 64);
    __shared__ double sdbl[4];
    if (lane == 0) sdbl[wave] = dval;
    __syncthreads();
    if (threadIdx.x == 0)
        partial2[blockIdx.x] = (sdbl[0] + sdbl[1]) + (sdbl[2] + sdbl[3]);
}

// ------- final reduce: out[b] = sum of partial2[b*2500 .. ) + bout -------
__global__ __launch_bounds__(256) void k_reduce(
        const double* __restrict__ partial2, const float* __restrict__ bout,
        float* __restrict__ out) {
    int b = blockIdx.x;
    int tid = threadIdx.x;
    double acc = 0.0;
    for (int i = tid; i < BLK_PER_BATCH; i += 256)
        acc += partial2[b * BLK_PER_BATCH + i];
    for (int off = 32; off; off >>= 1) acc += __shfl_down(acc, off, 64);
    __shared__ double sred[4];
    if ((tid & 63) == 0) sred[tid >> 6] = acc;
    __syncthreads();
    if (tid == 0)
        out[b] = (float)(((sred[0] + sred[1]) + (sred[2] + sred[3])) + (double)bout[0]);
}

extern "C" void kernel_launch(void* const* d_in, const int* in_sizes, int n_in,
                              void* d_out, int out_size, void* d_ws, size_t ws_size,
                              hipStream_t stream) {
    const float* x    = (const float*)d_in[0];
    const int*   ei   = (const int*)d_in[1];    // int32 (JAX x64 disabled)
    const float* W1   = (const float*)d_in[2];
    const float* b1   = (const float*)d_in[3];
    const float* W2   = (const float*)d_in[4];
    const float* b2   = (const float*)d_in[5];
    const float* Wout = (const float*)d_in[6];
    const float* bout = (const float*)d_in[7];
    float* out = (float*)d_out;

    // workspace layout — no aliasing, total ~63.9 MB (< 72.3 MB proven safe)
    char* ws = (char*)d_ws;
    size_t off = 0;
    int*      csr     = (int*)(ws + off);      off += (size_t)N_EDGE * 4;        // 10.24 MB
    unsigned* stage   = (unsigned*)(ws + off); off += (size_t)N_EDGE * 4;        // 10.24 MB
    float*    xW1s    = (float*)(ws + off);    off += (size_t)N_NODES * H1 * 4;  // 10.24 MB
    float*    agg1    = (float*)(ws + off);    off += (size_t)N_NODES * H1 * 4;  // 10.24 MB
    float*    h2s     = (float*)(ws + off);    off += (size_t)N_NODES * H2 * 4;  // 20.48 MB
    unsigned* ecnt    = (unsigned*)(ws + off); off += (size_t)N_NODES * 4;       // 0.32 MB
    unsigned* row_ptr = (unsigned*)(ws + off); off += (size_t)(N_NODES + 16) * 4;// 0.32 MB
    float*    dinv    = (float*)(ws + off);    off += (size_t)N_NODES * 4;       // 0.32 MB
    unsigned* excl    = (unsigned*)(ws + off); off += (size_t)N_NODES * 4;       // 0.32 MB
    unsigned* blocksum= (unsigned*)(ws + off); off += 512 * 4;
    unsigned* bbump   = (unsigned*)(ws + off); off += (size_t)NBKT * BBSTRIDE * 4; // 40 KB
    double*   partial2= (double*)(ws + off);   off += (size_t)G2_BLOCKS * 8;     // 0.16 MB
    (void)ws_size; (void)in_sizes; (void)n_in; (void)out_size;

    const int B = 256;
    k_init<<<(N_NODES + B - 1) / B, B, 0, stream>>>(ecnt);
    k_deg<<<(N_EDGE + B - 1) / B, B, 0, stream>>>(ei, ecnt);
    k_scan1<<<SCAN_NBLK, SCAN_B, 0, stream>>>(ecnt, excl, blocksum, dinv);
    k_scan2<<<1, 512, 0, stream>>>(blocksum);
    k_scan3<<<SCAN_NBLK, SCAN_B, 0, stream>>>(excl, blocksum, row_ptr, bbump);
    k_binfill<<<BF_BLOCKS, B, 0, stream>>>(ei, bbump, stage);
    k_place<<<NBKT, B, 0, stream>>>(row_ptr, stage, csr);

    k_gemm1<<<N_NODES / 8, B, 0, stream>>>(x, W1, dinv, xW1s);
    k_gather1<<<N_NODES / 4, B, 0, stream>>>(row_ptr, csr, xW1s, dinv, agg1);
    k_gemm2<<<N_NODES / 4, B, 0, stream>>>(agg1, b1, W2, dinv, h2s);
    k_gather2_final<<<G2_BLOCKS, B, 0, stream>>>(row_ptr, csr, h2s, dinv, b2, Wout, partial2);

    k_reduce<<<NB, B, 0, stream>>>(partial2, bout, out);
}

// Round 11
// 308.665 us; speedup vs baseline: 1.7450x; 1.2631x over previous
//
#include <hip/hip_runtime.h>

// Problem constants (match reference)
constexpr int   N_NODES = 80000;
constexpr int   N_EDGE  = 2560000;
constexpr int   IN_DIM  = 128;
constexpr int   H1      = 32;
constexpr int   H2      = 64;
constexpr int   NPB     = 10000;   // nodes per batch
constexpr int   NB      = 8;       // batches
constexpr int   G2_BLOCKS = N_NODES / 4;        // 20000 (4 nodes per block)
constexpr int   BLK_PER_BATCH = G2_BLOCKS / NB; // 2500

// binned-fill parameters
constexpr int   BKT_SHIFT = 7;                       // 128 nodes per bucket
constexpr int   BKT_N     = 1 << BKT_SHIFT;          // 128
constexpr int   NBKT      = N_NODES >> BKT_SHIFT;    // 625 (exact: 625*128=80000)
constexpr int   BBSTRIDE  = 16;                      // pad bucket counters to 64 B
constexpr int   BF_EPB    = 8192;                    // edges per binfill block
constexpr int   BF_BLOCKS = (N_EDGE + BF_EPB - 1) / BF_EPB;  // 313

// ---------------- init bucket counters (padded) to 0 ----------------
__global__ void k_initb(unsigned* __restrict__ bbump) {
    int i = blockIdx.x * blockDim.x + threadIdx.x;
    if (i < NBKT * BBSTRIDE) bbump[i] = 0u;
}

// ------- bucket count: LDS histogram, one global atomic per (block,bucket) --
__global__ __launch_bounds__(256) void k_bcount(
        const int* __restrict__ ei, unsigned* __restrict__ bbump) {
    __shared__ unsigned hist[NBKT];
    int t = threadIdx.x;
    int e0 = blockIdx.x * BF_EPB;
    int e1 = min(e0 + BF_EPB, N_EDGE);
    for (int i = t; i < NBKT; i += 256) hist[i] = 0u;
    __syncthreads();
    for (int e = e0 + t; e < e1; e += 256) {
        int d = ei[N_EDGE + e];
        atomicAdd(&hist[d >> BKT_SHIFT], 1u);
    }
    __syncthreads();
    for (int i = t; i < NBKT; i += 256) {
        unsigned h = hist[i];
        if (h) atomicAdd(&bbump[i * BBSTRIDE], h);
    }
}

// ------- bucket scan: bbase[] (exclusive) + re-seed bbump as bump ----------
__global__ __launch_bounds__(1024) void k_bscan(
        unsigned* __restrict__ bbump, unsigned* __restrict__ bbase) {
    __shared__ unsigned tmp[1024];
    int t = threadIdx.x;
    unsigned v = (t < NBKT) ? bbump[t * BBSTRIDE] : 0u;
    tmp[t] = v;
    for (int ofs = 1; ofs < 1024; ofs <<= 1) {
        __syncthreads();
        unsigned u = (t >= ofs) ? tmp[t - ofs] : 0u;
        __syncthreads();
        tmp[t] += u;
    }
    __syncthreads();
    if (t < NBKT) {
        unsigned base = tmp[t] - v;
        bbase[t] = base;
        bbump[t * BBSTRIDE] = base;   // reservation bump for k_binfill
    }
    if (t == 0) bbase[NBKT] = (unsigned)N_EDGE;
}

// ------- binned fill: stage[pos] = (src<<7)|d_local, dense per bucket ------
__global__ __launch_bounds__(256) void k_binfill(
        const int* __restrict__ ei, unsigned* __restrict__ bbump,
        unsigned* __restrict__ stage) {
    __shared__ unsigned hist[NBKT];
    __shared__ unsigned base[NBKT];
    int t = threadIdx.x;
    int e0 = blockIdx.x * BF_EPB;
    int e1 = min(e0 + BF_EPB, N_EDGE);
    for (int i = t; i < NBKT; i += 256) hist[i] = 0u;
    __syncthreads();
    for (int e = e0 + t; e < e1; e += 256) {
        int d = ei[N_EDGE + e];
        atomicAdd(&hist[d >> BKT_SHIFT], 1u);
    }
    __syncthreads();
    for (int i = t; i < NBKT; i += 256) {
        unsigned h = hist[i];
        base[i] = h ? atomicAdd(&bbump[i * BBSTRIDE], h) : 0u;
        hist[i] = 0u;
    }
    __syncthreads();
    for (int e = e0 + t; e < e1; e += 256) {
        int s = ei[e];
        int d = ei[N_EDGE + e];
        int bkt = d >> BKT_SHIFT;
        unsigned lp = atomicAdd(&hist[bkt], 1u);
        stage[base[bkt] + lp] =
            ((unsigned)s << BKT_SHIFT) | (unsigned)(d & (BKT_N - 1));
    }
}

// ------- place: per-bucket degrees (LDS) -> row_ptr, dinv, csr -------------
__global__ __launch_bounds__(256) void k_place(
        const unsigned* __restrict__ bbase, const unsigned* __restrict__ stage,
        int* __restrict__ csr, unsigned* __restrict__ row_ptr,
        float* __restrict__ dinv) {
    __shared__ unsigned cnt[BKT_N];
    __shared__ unsigned sc[BKT_N];
    __shared__ unsigned nb[BKT_N];
    int b = blockIdx.x;
    int t = threadIdx.x;
    unsigned beg = bbase[b], end = bbase[b + 1];
    if (t < BKT_N) cnt[t] = 0u;
    __syncthreads();
    // pass 1: node-local degree count
    for (unsigned j = beg + (unsigned)t; j < end; j += 256)
        atomicAdd(&cnt[stage[j] & (BKT_N - 1u)], 1u);
    __syncthreads();
    // inclusive scan of 128 counters
    if (t < BKT_N) sc[t] = cnt[t];
    for (int ofs = 1; ofs < BKT_N; ofs <<= 1) {
        __syncthreads();
        unsigned u = (t >= ofs && t < BKT_N) ? sc[t - ofs] : 0u;
        __syncthreads();
        if (t < BKT_N) sc[t] += u;
    }
    __syncthreads();
    if (t < BKT_N) {
        unsigned nodebase = beg + sc[t] - cnt[t];
        int node = (b << BKT_SHIFT) + t;
        row_ptr[node] = nodebase;
        dinv[node] = rsqrtf((float)(cnt[t] + 1u));   // +1 self loop
        nb[t] = nodebase;
    }
    if (b == NBKT - 1 && t == 0) row_ptr[N_NODES] = (unsigned)N_EDGE;
    __syncthreads();
    // pass 2: place (stage window is L2-hot; csr writes land in bucket window)
    for (unsigned j = beg + (unsigned)t; j < end; j += 256) {
        unsigned v = stage[j];
        unsigned pos = atomicAdd(&nb[v & (BKT_N - 1u)], 1u);
        csr[pos] = (int)(v >> BKT_SHIFT);
    }
}

// ---------------- GEMM1: xW1s = (x @ W1) * dinv[row]  (pre-scaled) --------
__global__ __launch_bounds__(256) void k_gemm1(
        const float* __restrict__ x, const float* __restrict__ W1,
        const float* __restrict__ dinv, float* __restrict__ xW1s) {
    __shared__ float W1s[IN_DIM * H1];   // 16 KB
    int tid = threadIdx.x;
    for (int i = tid; i < IN_DIM * H1; i += 256) W1s[i] = W1[i];
    __syncthreads();
    int r = tid >> 5, c = tid & 31;
    int row = blockIdx.x * 8 + r;
    if (row >= N_NODES) return;
    const float4* x4 = reinterpret_cast<const float4*>(x + (long long)row * IN_DIM);
    float acc = 0.f;
#pragma unroll
    for (int j = 0; j < IN_DIM / 4; ++j) {
        float4 xv = x4[j];
        acc += xv.x * W1s[(4 * j + 0) * H1 + c];
        acc += xv.y * W1s[(4 * j + 1) * H1 + c];
        acc += xv.z * W1s[(4 * j + 2) * H1 + c];
        acc += xv.w * W1s[(4 * j + 3) * H1 + c];
    }
    xW1s[row * H1 + c] = acc * dinv[row];
}

// ------- gather layer 1: agg1[d] = dinv[d] * (sum_e xW1s[src_e] + xW1s[d]) --
__global__ __launch_bounds__(256) void k_gather1(
        const unsigned* __restrict__ row_ptr, const int* __restrict__ csr,
        const float* __restrict__ xW1s, const float* __restrict__ dinv,
        float* __restrict__ agg1) {
    int wave = threadIdx.x >> 6;
    int lane = threadIdx.x & 63;
    int o = lane >> 3, t = lane & 7;
    int d = blockIdx.x * 4 + wave;
    if (d >= N_NODES) return;
    unsigned beg = row_ptr[d], end = row_ptr[d + 1];
    float4 acc = make_float4(0.f, 0.f, 0.f, 0.f);
    for (unsigned j = beg; j < end; j += 16) {
        unsigned j0 = j + (unsigned)o;
        unsigned j1 = j0 + 8u;
        int   s0 = (j0 < end) ? csr[j0] : 0;
        float m0 = (j0 < end) ? 1.f : 0.f;
        int   s1 = (j1 < end) ? csr[j1] : 0;
        float m1 = (j1 < end) ? 1.f : 0.f;
        float4 r0 = *reinterpret_cast<const float4*>(xW1s + (size_t)s0 * H1 + 4 * t);
        float4 r1 = *reinterpret_cast<const float4*>(xW1s + (size_t)s1 * H1 + 4 * t);
        acc.x += r0.x * m0 + r1.x * m1;
        acc.y += r0.y * m0 + r1.y * m1;
        acc.z += r0.z * m0 + r1.z * m1;
        acc.w += r0.w * m0 + r1.w * m1;
    }
#pragma unroll
    for (int m = 8; m <= 32; m <<= 1) {
        acc.x += __shfl_xor(acc.x, m, 64);
        acc.y += __shfl_xor(acc.y, m, 64);
        acc.z += __shfl_xor(acc.z, m, 64);
        acc.w += __shfl_xor(acc.w, m, 64);
    }
    if (lane < 8) {   // o == 0 octet writes the 32-feature row as 8x float4
        float dv = dinv[d];
        float4 self = *reinterpret_cast<const float4*>(xW1s + (size_t)d * H1 + 4 * t);
        float4 outv;
        outv.x = (acc.x + self.x) * dv;
        outv.y = (acc.y + self.y) * dv;
        outv.z = (acc.z + self.z) * dv;
        outv.w = (acc.w + self.w) * dv;
        *reinterpret_cast<float4*>(agg1 + (size_t)d * H1 + 4 * t) = outv;
    }
}

// ------- GEMM2: h2s = (relu(agg1+b1) @ W2) * dinv[row]  (pre-scaled) ------
__global__ __launch_bounds__(256) void k_gemm2(
        const float* __restrict__ agg1, const float* __restrict__ b1,
        const float* __restrict__ W2, const float* __restrict__ dinv,
        float* __restrict__ h2s) {
    __shared__ float W2s[H1 * H2];   // 8 KB
    __shared__ float b1s[H1];
    int tid = threadIdx.x;
    for (int i = tid; i < H1 * H2; i += 256) W2s[i] = W2[i];
    if (tid < H1) b1s[tid] = b1[tid];
    __syncthreads();
    int r = tid >> 6, c = tid & 63;
    int row = blockIdx.x * 4 + r;
    if (row >= N_NODES) return;
    float acc = 0.f;
#pragma unroll
    for (int k = 0; k < H1; ++k) {
        float hk = fmaxf(agg1[row * H1 + k] + b1s[k], 0.f);
        acc += hk * W2s[k * H2 + c];
    }
    h2s[row * H2 + c] = acc * dinv[row];
}

// ------- gather layer 2 FUSED with readout -------
__global__ __launch_bounds__(256) void k_gather2_final(
        const unsigned* __restrict__ row_ptr, const int* __restrict__ csr,
        const float* __restrict__ h2s, const float* __restrict__ dinv,
        const float* __restrict__ b2, const float* __restrict__ Wout,
        double* __restrict__ partial2) {
    int wave = threadIdx.x >> 6;
    int lane = threadIdx.x & 63;
    int q = lane >> 4, t = lane & 15;
    int d = blockIdx.x * 4 + wave;
    unsigned beg = row_ptr[d], end = row_ptr[d + 1];
    float4 acc = make_float4(0.f, 0.f, 0.f, 0.f);
    for (unsigned j = beg; j < end; j += 8) {
        unsigned j0 = j + (unsigned)q;
        unsigned j1 = j0 + 4u;
        int   s0 = (j0 < end) ? csr[j0] : 0;
        float m0 = (j0 < end) ? 1.f : 0.f;
        int   s1 = (j1 < end) ? csr[j1] : 0;
        float m1 = (j1 < end) ? 1.f : 0.f;
        float4 r0 = *reinterpret_cast<const float4*>(h2s + (size_t)s0 * H2 + 4 * t);
        float4 r1 = *reinterpret_cast<const float4*>(h2s + (size_t)s1 * H2 + 4 * t);
        acc.x += r0.x * m0 + r1.x * m1;
        acc.y += r0.y * m0 + r1.y * m1;
        acc.z += r0.z * m0 + r1.z * m1;
        acc.w += r0.w * m0 + r1.w * m1;
    }
#pragma unroll
    for (int m = 16; m <= 32; m <<= 1) {
        acc.x += __shfl_xor(acc.x, m, 64);
        acc.y += __shfl_xor(acc.y, m, 64);
        acc.z += __shfl_xor(acc.z, m, 64);
        acc.w += __shfl_xor(acc.w, m, 64);
    }
    float dv = dinv[d];
    float4 self = *reinterpret_cast<const float4*>(h2s + (size_t)d * H2 + 4 * t);
    float4 bb   = *reinterpret_cast<const float4*>(b2 + 4 * t);
    float4 ww   = *reinterpret_cast<const float4*>(Wout + (size_t)(d % NPB) * H2 + 4 * t);
    float v0 = fmaxf((acc.x + self.x) * dv + bb.x, 0.f) * ww.x;
    float v1 = fmaxf((acc.y + self.y) * dv + bb.y, 0.f) * ww.y;
    float v2 = fmaxf((acc.z + self.z) * dv + bb.z, 0.f) * ww.z;
    float v3 = fmaxf((acc.w + self.w) * dv + bb.w, 0.f) * ww.w;
    double dval = (double)v0 + (double)v1 + (double)v2 + (double)v3;
    dval += __shfl_down(dval, 8, 64);
    dval += __shfl_down(dval, 4, 64);
    dval += __shfl_down(dval, 2, 64);
    dval += __shfl_down(dval, 1, 64);
    __shared__ double sdbl[4];
    if (lane == 0) sdbl[wave] = dval;
    __syncthreads();
    if (threadIdx.x == 0)
        partial2[blockIdx.x] = (sdbl[0] + sdbl[1]) + (sdbl[2] + sdbl[3]);
}

// ------- final reduce: out[b] = sum of partial2[b*2500 .. ) + bout -------
__global__ __launch_bounds__(256) void k_reduce(
        const double* __restrict__ partial2, const float* __restrict__ bout,
        float* __restrict__ out) {
    int b = blockIdx.x;
    int tid = threadIdx.x;
    double acc = 0.0;
    for (int i = tid; i < BLK_PER_BATCH; i += 256)
        acc += partial2[b * BLK_PER_BATCH + i];
    for (int off = 32; off; off >>= 1) acc += __shfl_down(acc, off, 64);
    __shared__ double sred[4];
    if ((tid & 63) == 0) sred[tid >> 6] = acc;
    __syncthreads();
    if (tid == 0)
        out[b] = (float)(((sred[0] + sred[1]) + (sred[2] + sred[3])) + (double)bout[0]);
}

extern "C" void kernel_launch(void* const* d_in, const int* in_sizes, int n_in,
                              void* d_out, int out_size, void* d_ws, size_t ws_size,
                              hipStream_t stream) {
    const float* x    = (const float*)d_in[0];
    const int*   ei   = (const int*)d_in[1];    // int32 (JAX x64 disabled)
    const float* W1   = (const float*)d_in[2];
    const float* b1   = (const float*)d_in[3];
    const float* W2   = (const float*)d_in[4];
    const float* b2   = (const float*)d_in[5];
    const float* Wout = (const float*)d_in[6];
    const float* bout = (const float*)d_in[7];
    float* out = (float*)d_out;

    // workspace layout — no aliasing, total ~62.3 MB
    char* ws = (char*)d_ws;
    size_t off = 0;
    int*      csr     = (int*)(ws + off);      off += (size_t)N_EDGE * 4;        // 10.24 MB
    unsigned* stage   = (unsigned*)(ws + off); off += (size_t)N_EDGE * 4;        // 10.24 MB
    float*    xW1s    = (float*)(ws + off);    off += (size_t)N_NODES * H1 * 4;  // 10.24 MB
    float*    agg1    = (float*)(ws + off);    off += (size_t)N_NODES * H1 * 4;  // 10.24 MB
    float*    h2s     = (float*)(ws + off);    off += (size_t)N_NODES * H2 * 4;  // 20.48 MB
    unsigned* row_ptr = (unsigned*)(ws + off); off += (size_t)(N_NODES + 16) * 4;// 0.32 MB
    float*    dinv    = (float*)(ws + off);    off += (size_t)N_NODES * 4;       // 0.32 MB
    unsigned* bbump   = (unsigned*)(ws + off); off += (size_t)NBKT * BBSTRIDE * 4; // 40 KB
    unsigned* bbase   = (unsigned*)(ws + off); off += (size_t)(NBKT + 16) * 4;   // 2.6 KB
    double*   partial2= (double*)(ws + off);   off += (size_t)G2_BLOCKS * 8;     // 0.16 MB
    (void)ws_size; (void)in_sizes; (void)n_in; (void)out_size;

    const int B = 256;
    k_initb<<<(NBKT * BBSTRIDE + B - 1) / B, B, 0, stream>>>(bbump);
    k_bcount<<<BF_BLOCKS, B, 0, stream>>>(ei, bbump);
    k_bscan<<<1, 1024, 0, stream>>>(bbump, bbase);
    k_binfill<<<BF_BLOCKS, B, 0, stream>>>(ei, bbump, stage);
    k_place<<<NBKT, B, 0, stream>>>(bbase, stage, csr, row_ptr, dinv);

    k_gemm1<<<N_NODES / 8, B, 0, stream>>>(x, W1, dinv, xW1s);
    k_gather1<<<N_NODES / 4, B, 0, stream>>>(row_ptr, csr, xW1s, dinv, agg1);
    k_gemm2<<<N_NODES / 4, B, 0, stream>>>(agg1, b1, W2, dinv, h2s);
    k_gather2_final<<<G2_BLOCKS, B, 0, stream>>>(row_ptr, csr, h2s, dinv, b2, Wout, partial2);

    k_reduce<<<NB, B, 0, stream>>>(partial2, bout, out);
}

// Round 12
// 261.828 us; speedup vs baseline: 2.0571x; 1.1789x over previous
//
#include <hip/hip_runtime.h>
#include <hip/hip_fp16.h>

// Problem constants (match reference)
constexpr int   N_NODES = 80000;
constexpr int   N_EDGE  = 2560000;
constexpr int   IN_DIM  = 128;
constexpr int   H1      = 32;
constexpr int   H2      = 64;
constexpr int   NPB     = 10000;   // nodes per batch
constexpr int   NB      = 8;       // batches
constexpr int   G2_BLOCKS = N_NODES / 4;        // 20000 (4 nodes per block)
constexpr int   BLK_PER_BATCH = G2_BLOCKS / NB; // 2500

// binned-fill parameters
constexpr int   BKT_SHIFT = 7;                       // 128 nodes per bucket
constexpr int   BKT_N     = 1 << BKT_SHIFT;          // 128
constexpr int   NBKT      = N_NODES >> BKT_SHIFT;    // 625 (exact: 625*128=80000)
constexpr int   BBSTRIDE  = 16;                      // pad bucket counters to 64 B
constexpr int   BF_EPB    = 8192;                    // edges per binfill block
constexpr int   BF_BLOCKS = (N_EDGE + BF_EPB - 1) / BF_EPB;  // 313

// ---------------- init bucket counters (padded) to 0 ----------------
__global__ void k_initb(unsigned* __restrict__ bbump) {
    int i = blockIdx.x * blockDim.x + threadIdx.x;
    if (i < NBKT * BBSTRIDE) bbump[i] = 0u;
}

// ------- bucket count: LDS histogram, one global atomic per (block,bucket) --
__global__ __launch_bounds__(256) void k_bcount(
        const int* __restrict__ ei, unsigned* __restrict__ bbump) {
    __shared__ unsigned hist[NBKT];
    int t = threadIdx.x;
    int e0 = blockIdx.x * BF_EPB;
    int e1 = min(e0 + BF_EPB, N_EDGE);
    for (int i = t; i < NBKT; i += 256) hist[i] = 0u;
    __syncthreads();
    for (int e = e0 + t; e < e1; e += 256) {
        int d = ei[N_EDGE + e];
        atomicAdd(&hist[d >> BKT_SHIFT], 1u);
    }
    __syncthreads();
    for (int i = t; i < NBKT; i += 256) {
        unsigned h = hist[i];
        if (h) atomicAdd(&bbump[i * BBSTRIDE], h);
    }
}

// ------- bucket scan: bbase[] (exclusive) + re-seed bbump as bump ----------
__global__ __launch_bounds__(1024) void k_bscan(
        unsigned* __restrict__ bbump, unsigned* __restrict__ bbase) {
    __shared__ unsigned tmp[1024];
    int t = threadIdx.x;
    unsigned v = (t < NBKT) ? bbump[t * BBSTRIDE] : 0u;
    tmp[t] = v;
    for (int ofs = 1; ofs < 1024; ofs <<= 1) {
        __syncthreads();
        unsigned u = (t >= ofs) ? tmp[t - ofs] : 0u;
        __syncthreads();
        tmp[t] += u;
    }
    __syncthreads();
    if (t < NBKT) {
        unsigned base = tmp[t] - v;
        bbase[t] = base;
        bbump[t * BBSTRIDE] = base;   // reservation bump for k_binfill
    }
    if (t == 0) bbase[NBKT] = (unsigned)N_EDGE;
}

// ------- binned fill: stage[pos] = (src<<7)|d_local, dense per bucket ------
__global__ __launch_bounds__(256) void k_binfill(
        const int* __restrict__ ei, unsigned* __restrict__ bbump,
        unsigned* __restrict__ stage) {
    __shared__ unsigned hist[NBKT];
    __shared__ unsigned base[NBKT];
    int t = threadIdx.x;
    int e0 = blockIdx.x * BF_EPB;
    int e1 = min(e0 + BF_EPB, N_EDGE);
    for (int i = t; i < NBKT; i += 256) hist[i] = 0u;
    __syncthreads();
    for (int e = e0 + t; e < e1; e += 256) {
        int d = ei[N_EDGE + e];
        atomicAdd(&hist[d >> BKT_SHIFT], 1u);
    }
    __syncthreads();
    for (int i = t; i < NBKT; i += 256) {
        unsigned h = hist[i];
        base[i] = h ? atomicAdd(&bbump[i * BBSTRIDE], h) : 0u;
        hist[i] = 0u;
    }
    __syncthreads();
    for (int e = e0 + t; e < e1; e += 256) {
        int s = ei[e];
        int d = ei[N_EDGE + e];
        int bkt = d >> BKT_SHIFT;
        unsigned lp = atomicAdd(&hist[bkt], 1u);
        stage[base[bkt] + lp] =
            ((unsigned)s << BKT_SHIFT) | (unsigned)(d & (BKT_N - 1));
    }
}

// ------- place: per-bucket degrees (LDS) -> row_ptr, dinv, csr -------------
__global__ __launch_bounds__(256) void k_place(
        const unsigned* __restrict__ bbase, const unsigned* __restrict__ stage,
        int* __restrict__ csr, unsigned* __restrict__ row_ptr,
        float* __restrict__ dinv) {
    __shared__ unsigned cnt[BKT_N];
    __shared__ unsigned sc[BKT_N];
    __shared__ unsigned nb[BKT_N];
    int b = blockIdx.x;
    int t = threadIdx.x;
    unsigned beg = bbase[b], end = bbase[b + 1];
    if (t < BKT_N) cnt[t] = 0u;
    __syncthreads();
    for (unsigned j = beg + (unsigned)t; j < end; j += 256)
        atomicAdd(&cnt[stage[j] & (BKT_N - 1u)], 1u);
    __syncthreads();
    if (t < BKT_N) sc[t] = cnt[t];
    for (int ofs = 1; ofs < BKT_N; ofs <<= 1) {
        __syncthreads();
        unsigned u = (t >= ofs && t < BKT_N) ? sc[t - ofs] : 0u;
        __syncthreads();
        if (t < BKT_N) sc[t] += u;
    }
    __syncthreads();
    if (t < BKT_N) {
        unsigned nodebase = beg + sc[t] - cnt[t];
        int node = (b << BKT_SHIFT) + t;
        row_ptr[node] = nodebase;
        dinv[node] = rsqrtf((float)(cnt[t] + 1u));   // +1 self loop
        nb[t] = nodebase;
    }
    if (b == NBKT - 1 && t == 0) row_ptr[N_NODES] = (unsigned)N_EDGE;
    __syncthreads();
    for (unsigned j = beg + (unsigned)t; j < end; j += 256) {
        unsigned v = stage[j];
        unsigned pos = atomicAdd(&nb[v & (BKT_N - 1u)], 1u);
        csr[pos] = (int)(v >> BKT_SHIFT);
    }
}

// ------- GEMM1: xW1h = fp16( (x @ W1) * dinv[row] )  (pre-scaled) ---------
__global__ __launch_bounds__(256) void k_gemm1(
        const float* __restrict__ x, const float* __restrict__ W1,
        const float* __restrict__ dinv, __half* __restrict__ xW1h) {
    __shared__ float W1s[IN_DIM * H1];   // 16 KB
    int tid = threadIdx.x;
    for (int i = tid; i < IN_DIM * H1; i += 256) W1s[i] = W1[i];
    __syncthreads();
    int r = tid >> 5, c = tid & 31;
    int row = blockIdx.x * 8 + r;
    if (row >= N_NODES) return;
    const float4* x4 = reinterpret_cast<const float4*>(x + (long long)row * IN_DIM);
    float acc = 0.f;
#pragma unroll
    for (int j = 0; j < IN_DIM / 4; ++j) {
        float4 xv = x4[j];
        acc += xv.x * W1s[(4 * j + 0) * H1 + c];
        acc += xv.y * W1s[(4 * j + 1) * H1 + c];
        acc += xv.z * W1s[(4 * j + 2) * H1 + c];
        acc += xv.w * W1s[(4 * j + 3) * H1 + c];
    }
    xW1h[row * H1 + c] = __float2half(acc * dinv[row]);
}

// ------- gather layer 1 (fp16 rows, 64 B): 16 edge slots x 4 lanes --------
// agg1[d] = dinv[d] * (sum_e xW1h[src_e] + xW1h[d])   (f32 accumulate/out)
__global__ __launch_bounds__(256) void k_gather1(
        const unsigned* __restrict__ row_ptr, const int* __restrict__ csr,
        const __half* __restrict__ xW1h, const float* __restrict__ dinv,
        float* __restrict__ agg1) {
    int wave = threadIdx.x >> 6;
    int lane = threadIdx.x & 63;
    int q = lane >> 2, t = lane & 3;    // slot q in [0,16), features 8t..8t+7
    int d = blockIdx.x * 4 + wave;
    unsigned beg = row_ptr[d], end = row_ptr[d + 1];
    float acc[8] = {0.f, 0.f, 0.f, 0.f, 0.f, 0.f, 0.f, 0.f};
    for (unsigned j = beg; j < end; j += 32) {
        unsigned j0 = j + (unsigned)q;
        unsigned j1 = j0 + 16u;
        int   s0 = (j0 < end) ? csr[j0] : 0;
        float m0 = (j0 < end) ? 1.f : 0.f;
        int   s1 = (j1 < end) ? csr[j1] : 0;
        float m1 = (j1 < end) ? 1.f : 0.f;
        float4 raw0 = *reinterpret_cast<const float4*>(xW1h + (size_t)s0 * H1 + 8 * t);
        float4 raw1 = *reinterpret_cast<const float4*>(xW1h + (size_t)s1 * H1 + 8 * t);
        const __half2* h0 = reinterpret_cast<const __half2*>(&raw0);
        const __half2* h1 = reinterpret_cast<const __half2*>(&raw1);
#pragma unroll
        for (int i = 0; i < 4; ++i) {
            float2 f0 = __half22float2(h0[i]);
            float2 f1 = __half22float2(h1[i]);
            acc[2 * i]     += f0.x * m0 + f1.x * m1;
            acc[2 * i + 1] += f0.y * m0 + f1.y * m1;
        }
    }
#pragma unroll
    for (int m = 4; m <= 32; m <<= 1)
#pragma unroll
        for (int i = 0; i < 8; ++i)
            acc[i] += __shfl_xor(acc[i], m, 64);
    if (q == 0) {   // lanes 0..3 write the full 32-feature f32 row
        float dv = dinv[d];
        float4 sraw = *reinterpret_cast<const float4*>(xW1h + (size_t)d * H1 + 8 * t);
        const __half2* sh = reinterpret_cast<const __half2*>(&sraw);
        float o[8];
#pragma unroll
        for (int i = 0; i < 4; ++i) {
            float2 f = __half22float2(sh[i]);
            o[2 * i]     = (acc[2 * i] + f.x) * dv;
            o[2 * i + 1] = (acc[2 * i + 1] + f.y) * dv;
        }
        *reinterpret_cast<float4*>(agg1 + (size_t)d * H1 + 8 * t) =
            make_float4(o[0], o[1], o[2], o[3]);
        *reinterpret_cast<float4*>(agg1 + (size_t)d * H1 + 8 * t + 4) =
            make_float4(o[4], o[5], o[6], o[7]);
    }
}

// ------- GEMM2: h2h = fp16( (relu(agg1+b1) @ W2) * dinv[row] ) ------------
__global__ __launch_bounds__(256) void k_gemm2(
        const float* __restrict__ agg1, const float* __restrict__ b1,
        const float* __restrict__ W2, const float* __restrict__ dinv,
        __half* __restrict__ h2h) {
    __shared__ float W2s[H1 * H2];   // 8 KB
    __shared__ float b1s[H1];
    int tid = threadIdx.x;
    for (int i = tid; i < H1 * H2; i += 256) W2s[i] = W2[i];
    if (tid < H1) b1s[tid] = b1[tid];
    __syncthreads();
    int r = tid >> 6, c = tid & 63;
    int row = blockIdx.x * 4 + r;
    if (row >= N_NODES) return;
    float acc = 0.f;
#pragma unroll
    for (int k = 0; k < H1; ++k) {
        float hk = fmaxf(agg1[row * H1 + k] + b1s[k], 0.f);
        acc += hk * W2s[k * H2 + c];
    }
    h2h[row * H2 + c] = __float2half(acc * dinv[row]);
}

// ------- gather layer 2 FUSED with readout (fp16 rows, 128 B) -------------
// 8 edge slots x 8 lanes; f32 accumulate; epilogue + f64 block sum.
__global__ __launch_bounds__(256) void k_gather2_final(
        const unsigned* __restrict__ row_ptr, const int* __restrict__ csr,
        const __half* __restrict__ h2h, const float* __restrict__ dinv,
        const float* __restrict__ b2, const float* __restrict__ Wout,
        double* __restrict__ partial2) {
    int wave = threadIdx.x >> 6;
    int lane = threadIdx.x & 63;
    int o = lane >> 3, t = lane & 7;   // slot o in [0,8), features 8t..8t+7
    int d = blockIdx.x * 4 + wave;
    unsigned beg = row_ptr[d], end = row_ptr[d + 1];
    float acc[8] = {0.f, 0.f, 0.f, 0.f, 0.f, 0.f, 0.f, 0.f};
    for (unsigned j = beg; j < end; j += 16) {
        unsigned j0 = j + (unsigned)o;
        unsigned j1 = j0 + 8u;
        int   s0 = (j0 < end) ? csr[j0] : 0;
        float m0 = (j0 < end) ? 1.f : 0.f;
        int   s1 = (j1 < end) ? csr[j1] : 0;
        float m1 = (j1 < end) ? 1.f : 0.f;
        float4 raw0 = *reinterpret_cast<const float4*>(h2h + (size_t)s0 * H2 + 8 * t);
        float4 raw1 = *reinterpret_cast<const float4*>(h2h + (size_t)s1 * H2 + 8 * t);
        const __half2* h0 = reinterpret_cast<const __half2*>(&raw0);
        const __half2* h1 = reinterpret_cast<const __half2*>(&raw1);
#pragma unroll
        for (int i = 0; i < 4; ++i) {
            float2 f0 = __half22float2(h0[i]);
            float2 f1 = __half22float2(h1[i]);
            acc[2 * i]     += f0.x * m0 + f1.x * m1;
            acc[2 * i + 1] += f0.y * m0 + f1.y * m1;
        }
    }
#pragma unroll
    for (int m = 8; m <= 32; m <<= 1)
#pragma unroll
        for (int i = 0; i < 8; ++i)
            acc[i] += __shfl_xor(acc[i], m, 64);
    // epilogue: every lane has the totals for its feature octet 8t..8t+7
    float dv = dinv[d];
    float4 sraw = *reinterpret_cast<const float4*>(h2h + (size_t)d * H2 + 8 * t);
    const __half2* sh = reinterpret_cast<const __half2*>(&sraw);
    float4 bb0 = *reinterpret_cast<const float4*>(b2 + 8 * t);
    float4 bb1 = *reinterpret_cast<const float4*>(b2 + 8 * t + 4);
    const float* wrow = Wout + (size_t)(d % NPB) * H2 + 8 * t;
    float4 ww0 = *reinterpret_cast<const float4*>(wrow);
    float4 ww1 = *reinterpret_cast<const float4*>(wrow + 4);
    float self[8];
#pragma unroll
    for (int i = 0; i < 4; ++i) {
        float2 f = __half22float2(sh[i]);
        self[2 * i] = f.x; self[2 * i + 1] = f.y;
    }
    const float* bbp = &bb0.x;   // bb0,bb1 contiguous on stack? avoid: use arrays
    float bbv[8] = {bb0.x, bb0.y, bb0.z, bb0.w, bb1.x, bb1.y, bb1.z, bb1.w};
    float wwv[8] = {ww0.x, ww0.y, ww0.z, ww0.w, ww1.x, ww1.y, ww1.z, ww1.w};
    (void)bbp;
    double dval = 0.0;
#pragma unroll
    for (int i = 0; i < 8; ++i)
        dval += (double)(fmaxf((acc[i] + self[i]) * dv + bbv[i], 0.f) * wwv[i]);
    // sum across the 8 feature octets (lanes 0..7 of each octet group)
    dval += __shfl_down(dval, 4, 64);
    dval += __shfl_down(dval, 2, 64);
    dval += __shfl_down(dval, 1, 64);
    __shared__ double sdbl[4];
    if (lane == 0) sdbl[wave] = dval;
    __syncthreads();
    if (threadIdx.x == 0)
        partial2[blockIdx.x] = (sdbl[0] + sdbl[1]) + (sdbl[2] + sdbl[3]);
}

// ------- final reduce: out[b] = sum of partial2[b*2500 .. ) + bout -------
__global__ __launch_bounds__(256) void k_reduce(
        const double* __restrict__ partial2, const float* __restrict__ bout,
        float* __restrict__ out) {
    int b = blockIdx.x;
    int tid = threadIdx.x;
    double acc = 0.0;
    for (int i = tid; i < BLK_PER_BATCH; i += 256)
        acc += partial2[b * BLK_PER_BATCH + i];
    for (int off = 32; off; off >>= 1) acc += __shfl_down(acc, off, 64);
    __shared__ double sred[4];
    if ((tid & 63) == 0) sred[tid >> 6] = acc;
    __syncthreads();
    if (tid == 0)
        out[b] = (float)(((sred[0] + sred[1]) + (sred[2] + sred[3])) + (double)bout[0]);
}

extern "C" void kernel_launch(void* const* d_in, const int* in_sizes, int n_in,
                              void* d_out, int out_size, void* d_ws, size_t ws_size,
                              hipStream_t stream) {
    const float* x    = (const float*)d_in[0];
    const int*   ei   = (const int*)d_in[1];    // int32 (JAX x64 disabled)
    const float* W1   = (const float*)d_in[2];
    const float* b1   = (const float*)d_in[3];
    const float* W2   = (const float*)d_in[4];
    const float* b2   = (const float*)d_in[5];
    const float* Wout = (const float*)d_in[6];
    const float* bout = (const float*)d_in[7];
    float* out = (float*)d_out;

    // workspace layout — no aliasing, total ~47 MB
    char* ws = (char*)d_ws;
    size_t off = 0;
    int*      csr     = (int*)(ws + off);      off += (size_t)N_EDGE * 4;        // 10.24 MB
    unsigned* stage   = (unsigned*)(ws + off); off += (size_t)N_EDGE * 4;        // 10.24 MB
    __half*   xW1h    = (__half*)(ws + off);   off += (size_t)N_NODES * H1 * 2;  // 5.12 MB
    float*    agg1    = (float*)(ws + off);    off += (size_t)N_NODES * H1 * 4;  // 10.24 MB
    __half*   h2h     = (__half*)(ws + off);   off += (size_t)N_NODES * H2 * 2;  // 10.24 MB
    unsigned* row_ptr = (unsigned*)(ws + off); off += (size_t)(N_NODES + 16) * 4;// 0.32 MB
    float*    dinv    = (float*)(ws + off);    off += (size_t)N_NODES * 4;       // 0.32 MB
    unsigned* bbump   = (unsigned*)(ws + off); off += (size_t)NBKT * BBSTRIDE * 4; // 40 KB
    unsigned* bbase   = (unsigned*)(ws + off); off += (size_t)(NBKT + 16) * 4;   // 2.6 KB
    double*   partial2= (double*)(ws + off);   off += (size_t)G2_BLOCKS * 8;     // 0.16 MB
    (void)ws_size; (void)in_sizes; (void)n_in; (void)out_size;

    const int B = 256;
    k_initb<<<(NBKT * BBSTRIDE + B - 1) / B, B, 0, stream>>>(bbump);
    k_bcount<<<BF_BLOCKS, B, 0, stream>>>(ei, bbump);
    k_bscan<<<1, 1024, 0, stream>>>(bbump, bbase);
    k_binfill<<<BF_BLOCKS, B, 0, stream>>>(ei, bbump, stage);
    k_place<<<NBKT, B, 0, stream>>>(bbase, stage, csr, row_ptr, dinv);

    k_gemm1<<<N_NODES / 8, B, 0, stream>>>(x, W1, dinv, xW1h);
    k_gather1<<<N_NODES / 4, B, 0, stream>>>(row_ptr, csr, xW1h, dinv, agg1);
    k_gemm2<<<N_NODES / 4, B, 0, stream>>>(agg1, b1, W2, dinv, h2h);
    k_gather2_final<<<G2_BLOCKS, B, 0, stream>>>(row_ptr, csr, h2h, dinv, b2, Wout, partial2);

    k_reduce<<<NB, B, 0, stream>>>(partial2, bout, out);
}

// Round 13
// 236.066 us; speedup vs baseline: 2.2816x; 1.1091x over previous
//
#include <hip/hip_runtime.h>
#include <hip/hip_fp16.h>

// Problem constants (match reference)
constexpr int   N_NODES = 80000;
constexpr int   N_EDGE  = 2560000;
constexpr int   IN_DIM  = 128;
constexpr int   H1      = 32;
constexpr int   H2      = 64;
constexpr int   NPB     = 10000;   // nodes per batch
constexpr int   NB      = 8;       // batches
constexpr int   G2_BLOCKS = N_NODES / 4;        // 20000 (4 nodes per block)
constexpr int   BLK_PER_BATCH = G2_BLOCKS / NB; // 2500

// binned-fill parameters (static bucket capacity)
constexpr int   BKT_SHIFT = 7;                       // 128 nodes per bucket
constexpr int   BKT_N     = 1 << BKT_SHIFT;          // 128
constexpr int   NBKT      = N_NODES >> BKT_SHIFT;    // 625
constexpr int   BBSTRIDE  = 16;                      // pad bucket counters to 64 B
constexpr unsigned SBKT_CAP = 4608;                  // mean 4096 + 8 sigma
constexpr int   BF_EPB    = 8192;                    // edges per binfill block
constexpr int   BF_BLOCKS = (N_EDGE + BF_EPB - 1) / BF_EPB;  // 313
constexpr int   BF_THREADS = 512;

// ---------------- seed bucket bumps with static bases ----------------
__global__ void k_initb(unsigned* __restrict__ bbump) {
    int i = blockIdx.x * blockDim.x + threadIdx.x;
    if (i < NBKT) bbump[i * BBSTRIDE] = (unsigned)i * SBKT_CAP;
}

// ------- binned fill: stage[pos] = (src<<7)|d_local, dense per bucket ------
__global__ __launch_bounds__(BF_THREADS) void k_binfill(
        const int* __restrict__ ei, unsigned* __restrict__ bbump,
        unsigned* __restrict__ stage) {
    __shared__ unsigned hist[NBKT];
    __shared__ unsigned base[NBKT];
    int t = threadIdx.x;
    int e0 = blockIdx.x * BF_EPB;
    int e1 = min(e0 + BF_EPB, N_EDGE);
    for (int i = t; i < NBKT; i += BF_THREADS) hist[i] = 0u;
    __syncthreads();
    for (int e = e0 + t; e < e1; e += BF_THREADS) {
        int d = ei[N_EDGE + e];
        atomicAdd(&hist[d >> BKT_SHIFT], 1u);
    }
    __syncthreads();
    for (int i = t; i < NBKT; i += BF_THREADS) {
        unsigned h = hist[i];
        base[i] = h ? atomicAdd(&bbump[i * BBSTRIDE], h) : 0u;
        hist[i] = 0u;
    }
    __syncthreads();
    for (int e = e0 + t; e < e1; e += BF_THREADS) {
        int s = ei[e];
        int d = ei[N_EDGE + e];
        int bkt = d >> BKT_SHIFT;
        unsigned lp = atomicAdd(&hist[bkt], 1u);
        unsigned pos = base[bkt] + lp;
        if (pos < (unsigned)(bkt + 1) * SBKT_CAP)   // capacity guard (never hit)
            stage[pos] = ((unsigned)s << BKT_SHIFT) | (unsigned)(d & (BKT_N - 1));
    }
}

// ------- place: per-bucket degrees (LDS) -> row_ptr, rend, dinv, csr -------
__global__ __launch_bounds__(256) void k_place(
        const unsigned* __restrict__ bbump, const unsigned* __restrict__ stage,
        int* __restrict__ csr, unsigned* __restrict__ row_ptr,
        unsigned* __restrict__ rend, float* __restrict__ dinv) {
    __shared__ unsigned cnt[BKT_N];
    __shared__ unsigned sc[BKT_N];
    __shared__ unsigned nb[BKT_N];
    int b = blockIdx.x;
    int t = threadIdx.x;
    unsigned beg = (unsigned)b * SBKT_CAP;
    unsigned end = min(bbump[b * BBSTRIDE], (unsigned)(b + 1) * SBKT_CAP);
    if (t < BKT_N) cnt[t] = 0u;
    __syncthreads();
    for (unsigned j = beg + (unsigned)t; j < end; j += 256)
        atomicAdd(&cnt[stage[j] & (BKT_N - 1u)], 1u);
    __syncthreads();
    if (t < BKT_N) sc[t] = cnt[t];
    for (int ofs = 1; ofs < BKT_N; ofs <<= 1) {
        __syncthreads();
        unsigned u = (t >= ofs && t < BKT_N) ? sc[t - ofs] : 0u;
        __syncthreads();
        if (t < BKT_N) sc[t] += u;
    }
    __syncthreads();
    if (t < BKT_N) {
        unsigned nodebase = beg + sc[t] - cnt[t];
        int node = (b << BKT_SHIFT) + t;
        row_ptr[node] = nodebase;
        rend[node]    = nodebase + cnt[t];
        dinv[node] = rsqrtf((float)(cnt[t] + 1u));   // +1 self loop
        nb[t] = nodebase;
    }
    __syncthreads();
    for (unsigned j = beg + (unsigned)t; j < end; j += 256) {
        unsigned v = stage[j];
        unsigned pos = atomicAdd(&nb[v & (BKT_N - 1u)], 1u);
        csr[pos] = (int)(v >> BKT_SHIFT);
    }
}

// ------- GEMM1 (4-row register blocking): xW1h = fp16((x@W1)*dinv) --------
__global__ __launch_bounds__(256) void k_gemm1(
        const float* __restrict__ x, const float* __restrict__ W1,
        const float* __restrict__ dinv, __half* __restrict__ xW1h) {
    __shared__ float W1s[IN_DIM * H1];   // 16 KB
    int tid = threadIdx.x;
    for (int i = tid; i < IN_DIM * H1; i += 256) W1s[i] = W1[i];
    __syncthreads();
    int c = tid & 31, g = tid >> 5;           // 8 groups x 4 rows
    int row0 = blockIdx.x * 32 + g * 4;
    const float4* x0 = reinterpret_cast<const float4*>(x + (size_t)(row0 + 0) * IN_DIM);
    const float4* x1 = reinterpret_cast<const float4*>(x + (size_t)(row0 + 1) * IN_DIM);
    const float4* x2 = reinterpret_cast<const float4*>(x + (size_t)(row0 + 2) * IN_DIM);
    const float4* x3 = reinterpret_cast<const float4*>(x + (size_t)(row0 + 3) * IN_DIM);
    float acc0 = 0.f, acc1 = 0.f, acc2 = 0.f, acc3 = 0.f;
#pragma unroll 4
    for (int j = 0; j < IN_DIM / 4; ++j) {
        float4 a0 = x0[j], a1 = x1[j], a2 = x2[j], a3 = x3[j];
        float w0 = W1s[(4 * j + 0) * H1 + c];
        float w1 = W1s[(4 * j + 1) * H1 + c];
        float w2 = W1s[(4 * j + 2) * H1 + c];
        float w3 = W1s[(4 * j + 3) * H1 + c];
        acc0 += a0.x * w0 + a0.y * w1 + a0.z * w2 + a0.w * w3;
        acc1 += a1.x * w0 + a1.y * w1 + a1.z * w2 + a1.w * w3;
        acc2 += a2.x * w0 + a2.y * w1 + a2.z * w2 + a2.w * w3;
        acc3 += a3.x * w0 + a3.y * w1 + a3.z * w2 + a3.w * w3;
    }
    xW1h[(size_t)(row0 + 0) * H1 + c] = __float2half(acc0 * dinv[row0 + 0]);
    xW1h[(size_t)(row0 + 1) * H1 + c] = __float2half(acc1 * dinv[row0 + 1]);
    xW1h[(size_t)(row0 + 2) * H1 + c] = __float2half(acc2 * dinv[row0 + 2]);
    xW1h[(size_t)(row0 + 3) * H1 + c] = __float2half(acc3 * dinv[row0 + 3]);
}

// ------- gather layer 1 (fp16 rows, 64 B): 16 edge slots x 4 lanes --------
__global__ __launch_bounds__(256) void k_gather1(
        const unsigned* __restrict__ row_ptr, const unsigned* __restrict__ rend,
        const int* __restrict__ csr, const __half* __restrict__ xW1h,
        const float* __restrict__ dinv, float* __restrict__ agg1) {
    int wave = threadIdx.x >> 6;
    int lane = threadIdx.x & 63;
    int q = lane >> 2, t = lane & 3;    // slot q in [0,16), features 8t..8t+7
    int d = blockIdx.x * 4 + wave;
    unsigned beg = row_ptr[d], end = rend[d];
    float acc[8] = {0.f, 0.f, 0.f, 0.f, 0.f, 0.f, 0.f, 0.f};
    for (unsigned j = beg; j < end; j += 32) {
        unsigned j0 = j + (unsigned)q;
        unsigned j1 = j0 + 16u;
        int   s0 = (j0 < end) ? csr[j0] : 0;
        float m0 = (j0 < end) ? 1.f : 0.f;
        int   s1 = (j1 < end) ? csr[j1] : 0;
        float m1 = (j1 < end) ? 1.f : 0.f;
        float4 raw0 = *reinterpret_cast<const float4*>(xW1h + (size_t)s0 * H1 + 8 * t);
        float4 raw1 = *reinterpret_cast<const float4*>(xW1h + (size_t)s1 * H1 + 8 * t);
        const __half2* h0 = reinterpret_cast<const __half2*>(&raw0);
        const __half2* h1 = reinterpret_cast<const __half2*>(&raw1);
#pragma unroll
        for (int i = 0; i < 4; ++i) {
            float2 f0 = __half22float2(h0[i]);
            float2 f1 = __half22float2(h1[i]);
            acc[2 * i]     += f0.x * m0 + f1.x * m1;
            acc[2 * i + 1] += f0.y * m0 + f1.y * m1;
        }
    }
#pragma unroll
    for (int m = 4; m <= 32; m <<= 1)
#pragma unroll
        for (int i = 0; i < 8; ++i)
            acc[i] += __shfl_xor(acc[i], m, 64);
    if (q == 0) {   // lanes 0..3 write the full 32-feature f32 row
        float dv = dinv[d];
        float4 sraw = *reinterpret_cast<const float4*>(xW1h + (size_t)d * H1 + 8 * t);
        const __half2* sh = reinterpret_cast<const __half2*>(&sraw);
        float o[8];
#pragma unroll
        for (int i = 0; i < 4; ++i) {
            float2 f = __half22float2(sh[i]);
            o[2 * i]     = (acc[2 * i] + f.x) * dv;
            o[2 * i + 1] = (acc[2 * i + 1] + f.y) * dv;
        }
        *reinterpret_cast<float4*>(agg1 + (size_t)d * H1 + 8 * t) =
            make_float4(o[0], o[1], o[2], o[3]);
        *reinterpret_cast<float4*>(agg1 + (size_t)d * H1 + 8 * t + 4) =
            make_float4(o[4], o[5], o[6], o[7]);
    }
}

// ------- GEMM2: h2h = fp16( (relu(agg1+b1) @ W2) * dinv[row] ) ------------
__global__ __launch_bounds__(256) void k_gemm2(
        const float* __restrict__ agg1, const float* __restrict__ b1,
        const float* __restrict__ W2, const float* __restrict__ dinv,
        __half* __restrict__ h2h) {
    __shared__ float W2s[H1 * H2];   // 8 KB
    __shared__ float b1s[H1];
    int tid = threadIdx.x;
    for (int i = tid; i < H1 * H2; i += 256) W2s[i] = W2[i];
    if (tid < H1) b1s[tid] = b1[tid];
    __syncthreads();
    int r = tid >> 6, c = tid & 63;
    int row = blockIdx.x * 4 + r;
    if (row >= N_NODES) return;
    float acc = 0.f;
#pragma unroll
    for (int k = 0; k < H1; ++k) {
        float hk = fmaxf(agg1[row * H1 + k] + b1s[k], 0.f);
        acc += hk * W2s[k * H2 + c];
    }
    h2h[row * H2 + c] = __float2half(acc * dinv[row]);
}

// ------- gather layer 2 FUSED with readout (fp16 rows, 128 B) -------------
__global__ __launch_bounds__(256) void k_gather2_final(
        const unsigned* __restrict__ row_ptr, const unsigned* __restrict__ rend,
        const int* __restrict__ csr, const __half* __restrict__ h2h,
        const float* __restrict__ dinv, const float* __restrict__ b2,
        const float* __restrict__ Wout, double* __restrict__ partial2) {
    int wave = threadIdx.x >> 6;
    int lane = threadIdx.x & 63;
    int o = lane >> 3, t = lane & 7;   // slot o in [0,8), features 8t..8t+7
    int d = blockIdx.x * 4 + wave;
    unsigned beg = row_ptr[d], end = rend[d];
    float acc[8] = {0.f, 0.f, 0.f, 0.f, 0.f, 0.f, 0.f, 0.f};
    for (unsigned j = beg; j < end; j += 16) {
        unsigned j0 = j + (unsigned)o;
        unsigned j1 = j0 + 8u;
        int   s0 = (j0 < end) ? csr[j0] : 0;
        float m0 = (j0 < end) ? 1.f : 0.f;
        int   s1 = (j1 < end) ? csr[j1] : 0;
        float m1 = (j1 < end) ? 1.f : 0.f;
        float4 raw0 = *reinterpret_cast<const float4*>(h2h + (size_t)s0 * H2 + 8 * t);
        float4 raw1 = *reinterpret_cast<const float4*>(h2h + (size_t)s1 * H2 + 8 * t);
        const __half2* h0 = reinterpret_cast<const __half2*>(&raw0);
        const __half2* h1 = reinterpret_cast<const __half2*>(&raw1);
#pragma unroll
        for (int i = 0; i < 4; ++i) {
            float2 f0 = __half22float2(h0[i]);
            float2 f1 = __half22float2(h1[i]);
            acc[2 * i]     += f0.x * m0 + f1.x * m1;
            acc[2 * i + 1] += f0.y * m0 + f1.y * m1;
        }
    }
#pragma unroll
    for (int m = 8; m <= 32; m <<= 1)
#pragma unroll
        for (int i = 0; i < 8; ++i)
            acc[i] += __shfl_xor(acc[i], m, 64);
    float dv = dinv[d];
    float4 sraw = *reinterpret_cast<const float4*>(h2h + (size_t)d * H2 + 8 * t);
    const __half2* sh = reinterpret_cast<const __half2*>(&sraw);
    float4 bb0 = *reinterpret_cast<const float4*>(b2 + 8 * t);
    float4 bb1 = *reinterpret_cast<const float4*>(b2 + 8 * t + 4);
    const float* wrow = Wout + (size_t)(d % NPB) * H2 + 8 * t;
    float4 ww0 = *reinterpret_cast<const float4*>(wrow);
    float4 ww1 = *reinterpret_cast<const float4*>(wrow + 4);
    float self[8];
#pragma unroll
    for (int i = 0; i < 4; ++i) {
        float2 f = __half22float2(sh[i]);
        self[2 * i] = f.x; self[2 * i + 1] = f.y;
    }
    float bbv[8] = {bb0.x, bb0.y, bb0.z, bb0.w, bb1.x, bb1.y, bb1.z, bb1.w};
    float wwv[8] = {ww0.x, ww0.y, ww0.z, ww0.w, ww1.x, ww1.y, ww1.z, ww1.w};
    double dval = 0.0;
#pragma unroll
    for (int i = 0; i < 8; ++i)
        dval += (double)(fmaxf((acc[i] + self[i]) * dv + bbv[i], 0.f) * wwv[i]);
    dval += __shfl_down(dval, 4, 64);
    dval += __shfl_down(dval, 2, 64);
    dval += __shfl_down(dval, 1, 64);
    __shared__ double sdbl[4];
    if (lane == 0) sdbl[wave] = dval;
    __syncthreads();
    if (threadIdx.x == 0)
        partial2[blockIdx.x] = (sdbl[0] + sdbl[1]) + (sdbl[2] + sdbl[3]);
}

// ------- final reduce: out[b] = sum of partial2[b*2500 .. ) + bout -------
__global__ __launch_bounds__(256) void k_reduce(
        const double* __restrict__ partial2, const float* __restrict__ bout,
        float* __restrict__ out) {
    int b = blockIdx.x;
    int tid = threadIdx.x;
    double acc = 0.0;
    for (int i = tid; i < BLK_PER_BATCH; i += 256)
        acc += partial2[b * BLK_PER_BATCH + i];
    for (int off = 32; off; off >>= 1) acc += __shfl_down(acc, off, 64);
    __shared__ double sred[4];
    if ((tid & 63) == 0) sred[tid >> 6] = acc;
    __syncthreads();
    if (tid == 0)
        out[b] = (float)(((sred[0] + sred[1]) + (sred[2] + sred[3])) + (double)bout[0]);
}

extern "C" void kernel_launch(void* const* d_in, const int* in_sizes, int n_in,
                              void* d_out, int out_size, void* d_ws, size_t ws_size,
                              hipStream_t stream) {
    const float* x    = (const float*)d_in[0];
    const int*   ei   = (const int*)d_in[1];    // int32 (JAX x64 disabled)
    const float* W1   = (const float*)d_in[2];
    const float* b1   = (const float*)d_in[3];
    const float* W2   = (const float*)d_in[4];
    const float* b2   = (const float*)d_in[5];
    const float* Wout = (const float*)d_in[6];
    const float* bout = (const float*)d_in[7];
    float* out = (float*)d_out;

    // workspace layout — no aliasing, total ~50.5 MB
    constexpr size_t STATIC_SZ = (size_t)NBKT * SBKT_CAP;   // 2.88M entries
    char* ws = (char*)d_ws;
    size_t off = 0;
    int*      csr     = (int*)(ws + off);      off += STATIC_SZ * 4;             // 11.52 MB
    unsigned* stage   = (unsigned*)(ws + off); off += STATIC_SZ * 4;             // 11.52 MB
    __half*   xW1h    = (__half*)(ws + off);   off += (size_t)N_NODES * H1 * 2;  // 5.12 MB
    float*    agg1    = (float*)(ws + off);    off += (size_t)N_NODES * H1 * 4;  // 10.24 MB
    __half*   h2h     = (__half*)(ws + off);   off += (size_t)N_NODES * H2 * 2;  // 10.24 MB
    unsigned* row_ptr = (unsigned*)(ws + off); off += (size_t)N_NODES * 4;       // 0.32 MB
    unsigned* rend    = (unsigned*)(ws + off); off += (size_t)N_NODES * 4;       // 0.32 MB
    float*    dinv    = (float*)(ws + off);    off += (size_t)N_NODES * 4;       // 0.32 MB
    unsigned* bbump   = (unsigned*)(ws + off); off += (size_t)NBKT * BBSTRIDE * 4; // 40 KB
    double*   partial2= (double*)(ws + off);   off += (size_t)G2_BLOCKS * 8;     // 0.16 MB
    (void)ws_size; (void)in_sizes; (void)n_in; (void)out_size;

    const int B = 256;
    k_initb<<<(NBKT + B - 1) / B, B, 0, stream>>>(bbump);
    k_binfill<<<BF_BLOCKS, BF_THREADS, 0, stream>>>(ei, bbump, stage);
    k_place<<<NBKT, B, 0, stream>>>(bbump, stage, csr, row_ptr, rend, dinv);

    k_gemm1<<<N_NODES / 32, B, 0, stream>>>(x, W1, dinv, xW1h);
    k_gather1<<<N_NODES / 4, B, 0, stream>>>(row_ptr, rend, csr, xW1h, dinv, agg1);
    k_gemm2<<<N_NODES / 4, B, 0, stream>>>(agg1, b1, W2, dinv, h2h);
    k_gather2_final<<<G2_BLOCKS, B, 0, stream>>>(row_ptr, rend, csr, h2h, dinv, b2, Wout, partial2);

    k_reduce<<<NB, B, 0, stream>>>(partial2, bout, out);
}